// Round 1
// 718.475 us; speedup vs baseline: 1.1963x; 1.1963x over previous
//
#include <hip/hip_runtime.h>
#include <cmath>

// Shapes: B=8, N=4096, D=128, R=512, K=64
// d_in: 0 Ahat[8,4096,4096] 1 node_embs[8,4096,128] 2 mask(unused) 3 ht[8,512]
//       4 prev_Q[8,128,128] 5 W_map[512,128] 6 b_map[128]
//       7 Wu 8 Uu 9 bu 10 Wr 11 Ur 12 br 13 Wh 14 Uh 15 bh 16 static_W (all [128,128])
// d_out (fp32, 66576): out[8,64,128] @0, policy[8] @65536, scorer[8,128] @65544, entropy[8] @66568

__device__ __forceinline__ float sigmoidf_(float x){ return 1.0f/(1.0f+expf(-x)); }

// ---------- K1: scorer (split across all 256 threads) + scores ----------
// grid = 128 (16 blocks per batch), 256 threads
__global__ __launch_bounds__(256) void k_scores(const float* __restrict__ node_embs,
    const float* __restrict__ ht, const float* __restrict__ W_map,
    const float* __restrict__ b_map, float* __restrict__ scores,
    float* __restrict__ scorer_out) {
  int blk = blockIdx.x, t = threadIdx.x;
  int b = blk >> 4, part = blk & 15;
  __shared__ float htl[512];
  __shared__ float sp[256];
  __shared__ float scn[128];
  __shared__ float red[2];
  for (int e = t; e < 512; e += 256) htl[e] = ht[b*512 + e];
  __syncthreads();
  {
    // thread t = col + 128*half handles r in [half*256, half*256+256)
    int col = t & 127, half = t >> 7;
    const float* Wp = W_map + (size_t)(half*256)*128 + col;
    const float* hp = htl + half*256;
    float pacc = 0.f;
    #pragma unroll 8
    for (int r = 0; r < 256; ++r) pacc += hp[r] * Wp[(size_t)r*128];
    sp[t] = pacc;
  }
  __syncthreads();
  float scv = 0.f;
  if (t < 128) {
    float a = b_map[t] + sp[t] + sp[t + 128];
    scv = tanhf(a);
    float ss = scv*scv;
    #pragma unroll
    for (int off = 32; off; off >>= 1) ss += __shfl_xor(ss, off);
    if ((t & 63) == 0) red[t >> 6] = ss;
  }
  __syncthreads();
  float inv = 1.0f / sqrtf(red[0] + red[1]);
  if (t < 128) {
    scn[t] = scv * inv;
    if (part == 0) scorer_out[b*128 + t] = scv;
  }
  __syncthreads();
  int n = part*256 + t;
  const float4* row = (const float4*)(node_embs + ((size_t)(b*4096 + n)) * 128);
  float acc = 0.f;
  #pragma unroll
  for (int j = 0; j < 32; ++j) {
    float4 v = row[j];
    acc += v.x*scn[4*j] + v.y*scn[4*j+1] + v.z*scn[4*j+2] + v.w*scn[4*j+3];
  }
  scores[b*4096 + n] = acc;
}

// ---------- K2: softmax stats + top-64 (early-exit bsearch + parallel rank) + gather G + pool A ----------
// grid = 8 (one per batch), 256 threads
__global__ __launch_bounds__(256) void k_select(const float* __restrict__ scores,
    const float* __restrict__ node_embs, const float* __restrict__ Ahat,
    float* __restrict__ outPolicy, float* __restrict__ outEntropy,
    int* __restrict__ topk_idx, float* __restrict__ tanhs,
    float* __restrict__ G, float* __restrict__ A_ws) {
  int b = blockIdx.x, t = threadIdx.x;
  int wave = t >> 6, lane = t & 63;
  const float* s = scores + b*4096;

  __shared__ float redf[8];
  __shared__ int   redi[4];
  __shared__ unsigned int candK[256];
  __shared__ int   candI[256];
  __shared__ int   cnt;
  __shared__ int   idxl[64];
  __shared__ float selV[64];
  __shared__ float Al[64*65];
  __shared__ float di[64];

  float v[16];
  unsigned int u[16];
  #pragma unroll
  for (int j = 0; j < 16; ++j) {
    float x = s[j*256 + t];
    v[j] = x;
    unsigned int sb = __float_as_uint(x);
    u[j] = (sb & 0x80000000u) ? ~sb : (sb | 0x80000000u);
  }

  // ---- softmax stats ----
  float mx = v[0];
  #pragma unroll
  for (int j = 1; j < 16; ++j) mx = fmaxf(mx, v[j]);
  #pragma unroll
  for (int off = 32; off; off >>= 1) mx = fmaxf(mx, __shfl_xor(mx, off));
  if (lane == 0) redf[wave] = mx;
  __syncthreads();
  mx = fmaxf(fmaxf(redf[0], redf[1]), fmaxf(redf[2], redf[3]));
  __syncthreads();
  float S = 0.f, E1 = 0.f;
  #pragma unroll
  for (int j = 0; j < 16; ++j) { float e = expf(v[j] - mx); S += e; E1 += e*(v[j]-mx); }
  #pragma unroll
  for (int off = 32; off; off >>= 1) { S += __shfl_xor(S, off); E1 += __shfl_xor(E1, off); }
  if (lane == 0) { redf[wave] = S; redf[4 + wave] = E1; }
  __syncthreads();
  S  = redf[0] + redf[1] + redf[2] + redf[3];
  E1 = redf[4] + redf[5] + redf[6] + redf[7];
  float logS = logf(S);
  if (t == 0) outEntropy[b] = logS - E1 / S;
  __syncthreads();

  // ---- binary search for threshold; early exit when count == 64 exactly ----
  unsigned long long lo = 0ull, hi = 0xFFFFFFFFull;
  for (int it = 0; it < 32; ++it) {
    if (lo >= hi) break;   // uniform
    unsigned long long mid = lo + ((hi - lo + 1ull) >> 1);
    unsigned int midu = (unsigned int)mid;
    int c = 0;
    #pragma unroll
    for (int j = 0; j < 16; ++j) c += (u[j] >= midu) ? 1 : 0;
    #pragma unroll
    for (int off = 32; off; off >>= 1) c += __shfl_xor(c, off);
    if (lane == 0) redi[wave] = c;
    __syncthreads();
    int tot = redi[0] + redi[1] + redi[2] + redi[3];
    __syncthreads();
    bool fin = false;
    if (tot >= 64) { lo = mid; if (tot == 64) fin = true; }
    else hi = mid - 1ull;
    if (fin) break;        // uniform: set {u >= lo} is exactly the top-64
  }
  unsigned int Tstar = (unsigned int)lo;

  // ---- compact candidates (key >= T*), typically exactly 64 ----
  if (t == 0) cnt = 0;
  __syncthreads();
  #pragma unroll
  for (int j = 0; j < 16; ++j) {
    if (u[j] >= Tstar) {
      int p = atomicAdd(&cnt, 1);
      if (p < 256) { candK[p] = u[j]; candI[p] = j*256 + t; }
    }
  }
  __syncthreads();
  int nc = cnt < 256 ? cnt : 256;

  // ---- parallel rank: order = (val desc, idx asc), same as serial extraction ----
  if (t < nc) {
    unsigned long long mykey = ((unsigned long long)candK[t] << 32) | (unsigned int)(~candI[t]);
    int rank = 0;
    for (int j = 0; j < nc; ++j) {
      unsigned long long kj = ((unsigned long long)candK[j] << 32) | (unsigned int)(~candI[j]);
      rank += (kj > mykey) ? 1 : 0;
    }
    if (rank < 64) {
      unsigned int ku = candK[t];
      unsigned int sb = (ku & 0x80000000u) ? (ku & 0x7FFFFFFFu) : ~ku;
      float val = __uint_as_float(sb);
      int wi = candI[t];
      topk_idx[b*64 + rank] = wi;
      idxl[rank] = wi;
      tanhs[b*64 + rank] = tanhf(val);
      selV[rank] = val;
    }
  }
  __syncthreads();

  // ---- policy = mean(topk vals) - mx - logS ----
  if (t < 64) {
    float pv = selV[t];
    #pragma unroll
    for (int off = 32; off; off >>= 1) pv += __shfl_xor(pv, off);
    if (t == 0) outPolicy[b] = pv * (1.0f/64.0f) - mx - logS;
  }

  // ---- gather G[b,k,:] = node_embs[b, idx[k], :] ----
  for (int e = t; e < 8192; e += 256) {
    int k = e >> 7, d = e & 127;
    G[(size_t)b*8192 + e] = node_embs[((size_t)(b*4096 + idxl[k]))*128 + d];
  }

  // ---- pooled adjacency + sym-normalize ----
  const float* Ab = Ahat + (size_t)b * 4096 * 4096;
  for (int e = t; e < 4096; e += 256) {
    int p = e >> 6, q = e & 63;
    Al[p*65 + q] = Ab[(size_t)idxl[p]*4096 + idxl[q]];
  }
  __syncthreads();
  if (t < 64) {
    float ssum = 0.f;
    for (int p = 0; p < 64; ++p) ssum += Al[p*65 + t];
    di[t] = 1.0f / sqrtf(ssum);
  }
  __syncthreads();
  for (int e = t; e < 4096; e += 256) {
    int p = e >> 6, q = e & 63;
    A_ws[(size_t)b*4096 + e] = di[p] * di[q] * Al[p*65 + q];
  }
}

// ---------- K3: update & reset gates ----------
__global__ __launch_bounds__(128) void k_gru1(const float* __restrict__ G,
    const float* __restrict__ tanhs, const float* __restrict__ prevQ,
    const float* __restrict__ Wu, const float* __restrict__ Uu, const float* __restrict__ bu,
    const float* __restrict__ Wr, const float* __restrict__ Ur, const float* __restrict__ br,
    float* __restrict__ u_out, float* __restrict__ r_out) {
  int b = blockIdx.x >> 5, i0 = (blockIdx.x & 31) * 4, k = threadIdx.x;
  __shared__ float Gl[64*129];
  __shared__ float Wl[4][128], Ul[4][128], Wrl[4][128], Url[4][128];
  const float4* G4 = (const float4*)(G + (size_t)b*8192);
  for (int e4 = k; e4 < 2048; e4 += 128) {
    float4 vv = G4[e4];
    int rr = e4 >> 5, c = (e4 & 31) << 2;
    float* p = &Gl[rr*129 + c];
    p[0] = vv.x; p[1] = vv.y; p[2] = vv.z; p[3] = vv.w;
  }
  #pragma unroll
  for (int ii = 0; ii < 4; ++ii) {
    Wl[ii][k]  = Wu[(i0+ii)*128 + k]; Ul[ii][k]  = Uu[(i0+ii)*128 + k];
    Wrl[ii][k] = Wr[(i0+ii)*128 + k]; Url[ii][k] = Ur[(i0+ii)*128 + k];
  }
  __syncthreads();
  int km = k & 63;
  float tk = tanhs[b*64 + km];
  const float* Gr = Gl + km*129;
  const float* Q = prevQ + (size_t)b*16384;
  float aW[4] = {0,0,0,0}, aU[4] = {0,0,0,0}, aWr[4] = {0,0,0,0}, aUr[4] = {0,0,0,0};
  #pragma unroll 4
  for (int j = 0; j < 128; ++j) {
    float g = Gr[j], q = Q[j*128 + k];
    #pragma unroll
    for (int ii = 0; ii < 4; ++ii) {
      aW[ii]  += Wl[ii][j]  * g;  aU[ii]  += Ul[ii][j]  * q;
      aWr[ii] += Wrl[ii][j] * g;  aUr[ii] += Url[ii][j] * q;
    }
  }
  #pragma unroll
  for (int ii = 0; ii < 4; ++ii) {
    int i = i0 + ii; size_t o = ((size_t)b*128 + i)*128 + k;
    u_out[o] = sigmoidf_(aW[ii]*tk  + aU[ii]  + bu[i*128 + k]);
    r_out[o] = sigmoidf_(aWr[ii]*tk + aUr[ii] + br[i*128 + k]);
  }
}

// ---------- K4: h_cap + new_Q ----------
__global__ __launch_bounds__(128) void k_gru2(const float* __restrict__ G,
    const float* __restrict__ tanhs, const float* __restrict__ prevQ,
    const float* __restrict__ Wh, const float* __restrict__ Uh, const float* __restrict__ bh,
    const float* __restrict__ u_ws, const float* __restrict__ r_ws,
    float* __restrict__ Qn) {
  int b = blockIdx.x >> 5, i0 = (blockIdx.x & 31) * 4, k = threadIdx.x;
  __shared__ float Gl[64*129];
  __shared__ float Wl[4][128], Ul[4][128];
  const float4* G4 = (const float4*)(G + (size_t)b*8192);
  for (int e4 = k; e4 < 2048; e4 += 128) {
    float4 vv = G4[e4];
    int rr = e4 >> 5, c = (e4 & 31) << 2;
    float* p = &Gl[rr*129 + c];
    p[0] = vv.x; p[1] = vv.y; p[2] = vv.z; p[3] = vv.w;
  }
  #pragma unroll
  for (int ii = 0; ii < 4; ++ii) {
    Wl[ii][k] = Wh[(i0+ii)*128 + k]; Ul[ii][k] = Uh[(i0+ii)*128 + k];
  }
  __syncthreads();
  int km = k & 63;
  float tk = tanhs[b*64 + km];
  const float* Gr = Gl + km*129;
  const float* Q = prevQ + (size_t)b*16384;
  const float* Rw = r_ws + (size_t)b*16384;
  float aW[4] = {0,0,0,0}, aU[4] = {0,0,0,0};
  #pragma unroll 4
  for (int j = 0; j < 128; ++j) {
    float g = Gr[j];
    float rq = Rw[j*128 + k] * Q[j*128 + k];
    #pragma unroll
    for (int ii = 0; ii < 4; ++ii) { aW[ii] += Wl[ii][j]*g; aU[ii] += Ul[ii][j]*rq; }
  }
  #pragma unroll
  for (int ii = 0; ii < 4; ++ii) {
    int i = i0 + ii; size_t o = ((size_t)b*128 + i)*128 + k;
    float hc = tanhf(aW[ii]*tk + aU[ii] + bh[i*128 + k]);
    float uu = u_ws[o];
    float qq = Q[i*128 + k];
    Qn[o] = (1.f - uu)*qq + uu*hc;
  }
}

// ---------- K5: H0 = G@Qn; h1 = relu(A@H0); M = h1@Ws; out = (h1 + relu(A@M))/2 ----------
// G staged in LDS (broadcast reads), h1 kept in LDS (no HBM round-trip), single output write.
__global__ __launch_bounds__(512) void k_final(const float* __restrict__ G,
    const float* __restrict__ A_ws, const float* __restrict__ Qn,
    const float* __restrict__ Ws, float* __restrict__ out) {
  int b = blockIdx.x, t = threadIdx.x;
  int pg = t >> 7, d = t & 127;
  __shared__ float Al[64*64];     // 16 KB
  __shared__ float Gs[64*128];    // 32 KB: G, then h1
  __shared__ float buf[64*128];   // 32 KB: H0, then M
  const float* Gb = G  + (size_t)b*8192;
  const float* Q  = Qn + (size_t)b*16384;
  float* ob = out + (size_t)b*8192;
  for (int e = t; e < 4096; e += 512) Al[e] = A_ws[(size_t)b*4096 + e];
  for (int e = t; e < 8192; e += 512) Gs[e] = Gb[e];
  __syncthreads();

  // step 1: H0 = G @ Q
  float acc[16];
  #pragma unroll
  for (int ii = 0; ii < 16; ++ii) acc[ii] = 0.f;
  for (int j = 0; j < 128; j += 4) {
    float q0 = Q[(j+0)*128 + d];
    float q1 = Q[(j+1)*128 + d];
    float q2 = Q[(j+2)*128 + d];
    float q3 = Q[(j+3)*128 + d];
    #pragma unroll
    for (int ii = 0; ii < 16; ++ii) {
      float4 g = *(const float4*)&Gs[(pg + ii*4)*128 + j];
      acc[ii] += g.x*q0 + g.y*q1 + g.z*q2 + g.w*q3;
    }
  }
  #pragma unroll
  for (int ii = 0; ii < 16; ++ii) buf[(pg + ii*4)*128 + d] = acc[ii];
  __syncthreads();

  // step 2: h1 = relu(A @ H0) -> registers + Gs (overwrites G, no longer needed)
  float hv[16];
  #pragma unroll
  for (int ii = 0; ii < 16; ++ii) acc[ii] = 0.f;
  for (int q2 = 0; q2 < 64; ++q2) {
    float h0 = buf[q2*128 + d];
    #pragma unroll
    for (int ii = 0; ii < 16; ++ii) acc[ii] += Al[(pg + ii*4)*64 + q2] * h0;
  }
  #pragma unroll
  for (int ii = 0; ii < 16; ++ii) { hv[ii] = fmaxf(acc[ii], 0.f); Gs[(pg + ii*4)*128 + d] = hv[ii]; }
  __syncthreads();

  // step 3: M = h1 @ Ws (h1 from LDS)
  #pragma unroll
  for (int ii = 0; ii < 16; ++ii) acc[ii] = 0.f;
  for (int j = 0; j < 128; j += 4) {
    float w0 = Ws[(j+0)*128 + d];
    float w1 = Ws[(j+1)*128 + d];
    float w2 = Ws[(j+2)*128 + d];
    float w3 = Ws[(j+3)*128 + d];
    #pragma unroll
    for (int ii = 0; ii < 16; ++ii) {
      float4 h = *(const float4*)&Gs[(pg + ii*4)*128 + j];
      acc[ii] += h.x*w0 + h.y*w1 + h.z*w2 + h.w*w3;
    }
  }
  #pragma unroll
  for (int ii = 0; ii < 16; ++ii) buf[(pg + ii*4)*128 + d] = acc[ii];
  __syncthreads();

  // step 4: out = 0.5*(h1 + relu(A @ M))
  #pragma unroll
  for (int ii = 0; ii < 16; ++ii) acc[ii] = 0.f;
  for (int q2 = 0; q2 < 64; ++q2) {
    float mv = buf[q2*128 + d];
    #pragma unroll
    for (int ii = 0; ii < 16; ++ii) acc[ii] += Al[(pg + ii*4)*64 + q2] * mv;
  }
  #pragma unroll
  for (int ii = 0; ii < 16; ++ii)
    ob[(pg + ii*4)*128 + d] = 0.5f * (hv[ii] + fmaxf(acc[ii], 0.f));
}

extern "C" void kernel_launch(void* const* d_in, const int* in_sizes, int n_in,
                              void* d_out, int out_size, void* d_ws, size_t ws_size,
                              hipStream_t stream) {
  const float* Ahat      = (const float*)d_in[0];
  const float* node_embs = (const float*)d_in[1];
  const float* ht        = (const float*)d_in[3];
  const float* prev_Q    = (const float*)d_in[4];
  const float* W_map     = (const float*)d_in[5];
  const float* b_map     = (const float*)d_in[6];
  const float* Wu = (const float*)d_in[7];
  const float* Uu = (const float*)d_in[8];
  const float* bu = (const float*)d_in[9];
  const float* Wr = (const float*)d_in[10];
  const float* Ur = (const float*)d_in[11];
  const float* br = (const float*)d_in[12];
  const float* Wh = (const float*)d_in[13];
  const float* Uh = (const float*)d_in[14];
  const float* bh = (const float*)d_in[15];
  const float* staticW = (const float*)d_in[16];

  float* out = (float*)d_out;
  float* ws  = (float*)d_ws;
  float* scores    = ws;                 // 32768
  int*   topk_idx  = (int*)(ws + 32768); // 512
  float* tanhs     = ws + 33280;         // 512
  float* G         = ws + 33792;         // 65536
  float* u_ws      = ws + 99328;         // 131072
  float* r_ws      = ws + 230400;        // 131072
  float* Qn        = ws + 361472;        // 131072
  float* A_ws      = ws + 492544;        // 32768

  float* policy  = out + 65536;
  float* scr_out = out + 65544;
  float* entropy = out + 66568;

  k_scores<<<128, 256, 0, stream>>>(node_embs, ht, W_map, b_map, scores, scr_out);
  k_select<<<8, 256, 0, stream>>>(scores, node_embs, Ahat, policy, entropy,
                                  topk_idx, tanhs, G, A_ws);
  k_gru1  <<<256, 128, 0, stream>>>(G, tanhs, prev_Q, Wu, Uu, bu, Wr, Ur, br, u_ws, r_ws);
  k_gru2  <<<256, 128, 0, stream>>>(G, tanhs, prev_Q, Wh, Uh, bh, u_ws, r_ws, Qn);
  k_final <<<8, 512, 0, stream>>>(G, A_ws, Qn, staticW, out);
}